// Round 8
// baseline (194.320 us; speedup 1.0000x reference)
//
#include <hip/hip_runtime.h>
#include <hip/hip_bf16.h>

typedef __attribute__((ext_vector_type(8))) short bf16x8;
typedef __attribute__((ext_vector_type(4))) float f32x4;

#define S_LEN 2048
#define EMB   1024
#define NH    16
#define HD    64

// XOR-swizzled LDS addressing: 64-col bf16 tiles, 8-elem (16 B) chunks.
// elem(row, chunk) = row*64 + ((chunk ^ (row&7))*8).
// Staging writes AND all fragment reads are bank-uniform.
// Verified round 6/7: SQ_LDS_BANK_CONFLICT == 0.
__device__ inline int swz(int row, int chunk) {
  return row * 64 + ((chunk ^ (row & 7)) << 3);
}

// K-row permutation: storing K row s at position [s5,s2,s4,s3,s1,s0] makes
// the exp(S^T) C-layout registers exactly the mfma_16x16x32 A-fragment for
// natural-order V; PV then uses K=32 MFMA with b128 V reads, no fixup.
// Correctness verified rounds 6-7 (absmax 4.88e-4).
__device__ inline int kperm(int s) {
  return (s & 0x23) | ((s & 0x04) << 2) | ((s & 0x18) >> 1);
}

// Convert 8 contiguous f32 -> 8 bf16 (RNE) packed in a uint4, optional scale.
__device__ inline uint4 cvt8(const float* __restrict__ src, float scale) {
  float4 f0 = ((const float4*)src)[0];
  float4 f1 = ((const float4*)src)[1];
  __hip_bfloat16 t[8];
  t[0] = __float2bfloat16(f0.x * scale);
  t[1] = __float2bfloat16(f0.y * scale);
  t[2] = __float2bfloat16(f0.z * scale);
  t[3] = __float2bfloat16(f0.w * scale);
  t[4] = __float2bfloat16(f1.x * scale);
  t[5] = __float2bfloat16(f1.y * scale);
  t[6] = __float2bfloat16(f1.z * scale);
  t[7] = __float2bfloat16(f1.w * scale);
  return *(uint4*)t;
}

// ---------------------------------------------------------------------------
// prep: z<2 -> K/V reformat for batch b=z; z==2 -> W f32->bf16 convert.
//   Kb[((b*NH+h)*S + s)*64 + d]  (head-major, rows = keys)
//   Vt[((b*NH+h)*64 + d)*S + s]  (transposed, rows = dims)
// ---------------------------------------------------------------------------
__global__ __launch_bounds__(256)
void prep(const float* __restrict__ K, const float* __restrict__ V,
          const float* __restrict__ W,
          __hip_bfloat16* __restrict__ Kb, __hip_bfloat16* __restrict__ Vt,
          __hip_bfloat16* __restrict__ Wb) {
  const int tid = threadIdx.x;
  if (blockIdx.z == 2) {   // W convert: 512 virtual blocks x 2048 elems
    const int widx = blockIdx.y * 32 + blockIdx.x;
    const int i = (widx * 256 + tid) * 8;
    *(uint4*)(Wb + i) = cvt8(W + i, 1.0f);
    return;
  }
  __shared__ float vt[64 * 65];
  const int st = blockIdx.x, h = blockIdx.y, b = blockIdx.z;
  const size_t srcbase = ((size_t)(b * S_LEN + st * 64)) * EMB + h * HD;
  const size_t kvb = ((size_t)(b * NH + h) * S_LEN + st * 64) * HD;
  const size_t vtb = ((size_t)(b * NH + h) * HD) * S_LEN + st * 64;

  for (int c = tid; c < 512; c += 256) {
    const int r = c >> 3, c8 = (c & 7) * 8;
    *(uint4*)(Kb + kvb + r * HD + c8) = cvt8(K + srcbase + (size_t)r * EMB + c8, 1.0f);
    const float* vsrc = V + srcbase + (size_t)r * EMB + c8;
    float4 a = ((const float4*)vsrc)[0];
    float4 d4 = ((const float4*)vsrc)[1];
    float tv[8] = {a.x, a.y, a.z, a.w, d4.x, d4.y, d4.z, d4.w};
    #pragma unroll
    for (int j = 0; j < 8; ++j) vt[r * 65 + c8 + j] = tv[j];
  }
  __syncthreads();
  for (int c = tid; c < 512; c += 256) {
    const int d = c >> 3, s8 = (c & 7) * 8;
    __hip_bfloat16 t[8];
    #pragma unroll
    for (int j = 0; j < 8; ++j)
      t[j] = __float2bfloat16(vt[(s8 + j) * 65 + d]);
    *(uint4*)(Vt + vtb + (size_t)d * S_LEN + s8) = *(uint4*)t;
  }
}

// ---------------------------------------------------------------------------
// Flash attention v8 = v7 + 2 query groups per wave (qn=0,1): each K/V LDS
// fragment read feeds TWO MFMAs, halving the dominant per-CU LDS-read work
// (round-7 model: 46 us of 62.5 us was LDS pipe). 512 thr = 8 waves x 32
// queries = 256 q/block; grid 256 = exactly 1 block/CU.
// Spill-proofing (round-6 lesson): all register arrays flat 1-D, constant
// indices; __launch_bounds__(512,2) -> 256-VGPR cap for the ~120-reg set.
// S^T = K Q^T; exp(S^T) is directly the PV A-operand (kperm'd K rows,
// K=32 PV MFMAs). XOR swizzle: 0 bank conflicts. 1 barrier/iter.
// ---------------------------------------------------------------------------
__global__ __launch_bounds__(512, 2)
void attn_fwd(const float* __restrict__ Q,
              const __hip_bfloat16* __restrict__ Kb,
              const __hip_bfloat16* __restrict__ Vt,
              __hip_bfloat16* __restrict__ O)
{
  __shared__ __align__(16) __hip_bfloat16 qs[256 * 64];     // 32 KB
  __shared__ __align__(16) __hip_bfloat16 ks[2][64 * 64];   // 16 KB [key][dim]
  __shared__ __align__(16) __hip_bfloat16 vs[2][64 * 64];   // 16 KB [dim][key]

  const int qt   = blockIdx.x;
  const int h    = blockIdx.y;
  const int b    = blockIdx.z;
  const int tid  = threadIdx.x;
  const int wave = tid >> 6;
  const int lane = tid & 63;
  const int ln   = lane & 15;
  const int qd   = lane >> 4;

  const size_t baseQ = ((size_t)(b * S_LEN + qt * 256)) * EMB + h * HD;
  const size_t kvb   = ((size_t)(b * NH + h) * S_LEN) * HD;
  const size_t vtb   = ((size_t)(b * NH + h) * HD) * S_LEN;

  // K/V staging: 512 chunks per tile, 512 threads -> 1 chunk each
  const int r0 = tid >> 3, cc = tid & 7;
  const int kpos = swz(kperm(r0), cc);   // loop-invariant write addrs
  const int vpos = swz(r0, cc);

  // prefetch tile 0
  uint4 kreg = *(const uint4*)(Kb + kvb + (size_t)r0 * HD + cc * 8);
  uint4 vreg = *(const uint4*)(Vt + vtb + (size_t)r0 * S_LEN + cc * 8);

  // stage Q: 256 rows x 8 chunks = 2048 chunks, 4 per thread
  const float qscale = 0.125f * 1.44269504088896f;   // 1/sqrt(64) * log2(e)
  #pragma unroll
  for (int i = 0; i < 4; ++i) {
    const int c = tid + 512 * i, row = c >> 3, ch = c & 7;
    *(uint4*)&qs[swz(row, ch)] = cvt8(Q + baseQ + (size_t)row * EMB + ch * 8, qscale);
  }
  // write tile 0, prefetch tile 1
  *(uint4*)&ks[0][kpos] = kreg;
  *(uint4*)&vs[0][vpos] = vreg;
  kreg = *(const uint4*)(Kb + kvb + (size_t)(64 + r0) * HD + cc * 8);
  vreg = *(const uint4*)(Vt + vtb + (size_t)r0 * S_LEN + 64 + cc * 8);
  __syncthreads();   // qs + buf0 ready

  // Q B-fragments (n = query = ln, k = qd*8+j), loop-invariant
  bf16x8 aq0[2], aq1[2];
  #pragma unroll
  for (int kh = 0; kh < 2; ++kh) {
    aq0[kh] = *(const bf16x8*)&qs[swz(wave * 32 + ln,      kh * 4 + qd)];
    aq1[kh] = *(const bf16x8*)&qs[swz(wave * 32 + 16 + ln, kh * 4 + qd)];
  }

  f32x4 oacc0[4] = {}, oacc1[4] = {};   // [dn]; C: col=dim=ln, row=qd*4+r
  float lsum0 = 0.f, lsum1 = 0.f;

  for (int kt = 0; kt < S_LEN / 64; ++kt) {
    const int cur = kt & 1;
    if (kt + 1 < S_LEN / 64) {     // regs loaded one full iter ago: no stall
      *(uint4*)&ks[1 - cur][kpos] = kreg;
      *(uint4*)&vs[1 - cur][vpos] = vreg;
      if (kt + 2 < S_LEN / 64) {
        kreg = *(const uint4*)(Kb + kvb + (size_t)((kt + 2) * 64 + r0) * HD + cc * 8);
        vreg = *(const uint4*)(Vt + vtb + (size_t)r0 * S_LEN + (kt + 2) * 64 + cc * 8);
      }
    }

    // ---- S^T = K Q^T (rows = permuted keys); K fragments shared by qn ----
    f32x4 sf0[4], sf1[4];
    #pragma unroll
    for (int kt16 = 0; kt16 < 4; ++kt16) {
      bf16x8 ak0 = *(const bf16x8*)&ks[cur][swz(kt16 * 16 + ln, qd)];
      bf16x8 ak1 = *(const bf16x8*)&ks[cur][swz(kt16 * 16 + ln, 4 + qd)];
      f32x4 a0 = {}, a1 = {};
      a0 = __builtin_amdgcn_mfma_f32_16x16x32_bf16(ak0, aq0[0], a0, 0, 0, 0);
      a0 = __builtin_amdgcn_mfma_f32_16x16x32_bf16(ak1, aq0[1], a0, 0, 0, 0);
      a1 = __builtin_amdgcn_mfma_f32_16x16x32_bf16(ak0, aq1[0], a1, 0, 0, 0);
      a1 = __builtin_amdgcn_mfma_f32_16x16x32_bf16(ak1, aq1[1], a1, 0, 0, 0);
      sf0[kt16] = a0;
      sf1[kt16] = a1;
    }

    // ---- P = exp2(S'); pack straight into K=32 A-fragments ----
    // key at k-index qd*8+j lives at S^T tile kt16 = t*2+(j>>2), reg j&3
    bf16x8 ap0[2], ap1[2];
    #pragma unroll
    for (int t = 0; t < 2; ++t)
      #pragma unroll
      for (int j = 0; j < 8; ++j) {
        const float p0 = exp2f(sf0[t * 2 + (j >> 2)][j & 3]);
        const float p1 = exp2f(sf1[t * 2 + (j >> 2)][j & 3]);
        lsum0 += p0;
        lsum1 += p1;
        __hip_bfloat16 h0 = __float2bfloat16(p0);
        __hip_bfloat16 h1 = __float2bfloat16(p1);
        ap0[t][j] = *(short*)&h0;
        ap1[t][j] = *(short*)&h1;
      }

    // ---- O += P V : K=32 MFMA, b128 V reads shared by qn ----
    #pragma unroll
    for (int t = 0; t < 2; ++t)
      #pragma unroll
      for (int dn = 0; dn < 4; ++dn) {
        bf16x8 bv = *(const bf16x8*)&vs[cur][swz(dn * 16 + ln, t * 4 + qd)];
        oacc0[dn] = __builtin_amdgcn_mfma_f32_16x16x32_bf16(ap0[t], bv, oacc0[dn], 0, 0, 0);
        oacc1[dn] = __builtin_amdgcn_mfma_f32_16x16x32_bf16(ap1[t], bv, oacc1[dn], 0, 0, 0);
      }

    __syncthreads();   // single barrier per iteration
  }

  // ---- epilogue: reduce lsum across quads, redistribute, normalize ----
  lsum0 += __shfl_xor(lsum0, 16);
  lsum0 += __shfl_xor(lsum0, 32);
  lsum1 += __shfl_xor(lsum1, 16);
  lsum1 += __shfl_xor(lsum1, 32);
  #pragma unroll
  for (int r = 0; r < 4; ++r) {
    const float inv0 = 1.f / __shfl(lsum0, qd * 4 + r);
    const float inv1 = 1.f / __shfl(lsum1, qd * 4 + r);
    const int row0 = wave * 32 + qd * 4 + r;
    const int row1 = row0 + 16;
    #pragma unroll
    for (int dn = 0; dn < 4; ++dn) {
      O[baseQ + (size_t)row0 * EMB + dn * 16 + ln] =
          __float2bfloat16(oacc0[dn][r] * inv0);
      O[baseQ + (size_t)row1 * EMB + dn * 16 + ln] =
          __float2bfloat16(oacc1[dn][r] * inv1);
    }
  }
}

// ---------------------------------------------------------------------------
// Projection: Out = PReLU(X @ W^T + b). 128x128 tile, 512 thr = 8 waves in a
// 4(M) x 2(N) grid (32 rows x 64 cols each). XOR-swizzled LDS (conflict-
// free), double-buffered, one barrier per k-iteration.
// ---------------------------------------------------------------------------
__global__ __launch_bounds__(512, 2)
void proj_prelu(const __hip_bfloat16* __restrict__ X,
                const __hip_bfloat16* __restrict__ Wb,
                const float* __restrict__ Bv,
                const float* __restrict__ Pa,
                float* __restrict__ Out)
{
  __shared__ __align__(16) __hip_bfloat16 xs[2][128 * 64];   // 32 KB
  __shared__ __align__(16) __hip_bfloat16 wsm[2][128 * 64];  // 32 KB

  const int m0   = blockIdx.x * 128;
  const int n0   = blockIdx.y * 128;
  const int tid  = threadIdx.x;
  const int wave = tid >> 6;
  const int wm   = wave >> 1;      // 0..3 : 32-row strip
  const int wn   = wave & 1;       // 0..1 : 64-col strip
  const int lane = tid & 63;
  const int ln   = lane & 15;
  const int qd   = lane >> 4;

  // staging: 1024 chunks per array / 512 thr = 2 each
  const int ra = tid >> 3, rb = ra + 64, cc = tid & 7;
  const int pa = swz(ra, cc), pb = swz(rb, cc);

  f32x4 acc[2][4] = {};   // [mf][nf]

  uint4 xrg[2], wrg[2];
  xrg[0] = *(const uint4*)(X  + (size_t)(m0 + ra) * EMB + cc * 8);
  xrg[1] = *(const uint4*)(X  + (size_t)(m0 + rb) * EMB + cc * 8);
  wrg[0] = *(const uint4*)(Wb + (size_t)(n0 + ra) * EMB + cc * 8);
  wrg[1] = *(const uint4*)(Wb + (size_t)(n0 + rb) * EMB + cc * 8);
  *(uint4*)&xs[0][pa]  = xrg[0];  *(uint4*)&xs[0][pb]  = xrg[1];
  *(uint4*)&wsm[0][pa] = wrg[0];  *(uint4*)&wsm[0][pb] = wrg[1];
  xrg[0] = *(const uint4*)(X  + (size_t)(m0 + ra) * EMB + 64 + cc * 8);
  xrg[1] = *(const uint4*)(X  + (size_t)(m0 + rb) * EMB + 64 + cc * 8);
  wrg[0] = *(const uint4*)(Wb + (size_t)(n0 + ra) * EMB + 64 + cc * 8);
  wrg[1] = *(const uint4*)(Wb + (size_t)(n0 + rb) * EMB + 64 + cc * 8);
  __syncthreads();

  for (int kt = 0; kt < EMB / 64; ++kt) {
    const int cur = kt & 1;
    if (kt + 1 < EMB / 64) {
      *(uint4*)&xs[1 - cur][pa]  = xrg[0];  *(uint4*)&xs[1 - cur][pb]  = xrg[1];
      *(uint4*)&wsm[1 - cur][pa] = wrg[0];  *(uint4*)&wsm[1 - cur][pb] = wrg[1];
      if (kt + 2 < EMB / 64) {
        const int ko = (kt + 2) * 64;
        xrg[0] = *(const uint4*)(X  + (size_t)(m0 + ra) * EMB + ko + cc * 8);
        xrg[1] = *(const uint4*)(X  + (size_t)(m0 + rb) * EMB + ko + cc * 8);
        wrg[0] = *(const uint4*)(Wb + (size_t)(n0 + ra) * EMB + ko + cc * 8);
        wrg[1] = *(const uint4*)(Wb + (size_t)(n0 + rb) * EMB + ko + cc * 8);
      }
    }

    #pragma unroll
    for (int kh = 0; kh < 2; ++kh) {
      bf16x8 ax[2], bw[4];
      #pragma unroll
      for (int mf = 0; mf < 2; ++mf)
        ax[mf] = *(const bf16x8*)&xs[cur][swz(wm * 32 + mf * 16 + ln, kh * 4 + qd)];
      #pragma unroll
      for (int nf = 0; nf < 4; ++nf)
        bw[nf] = *(const bf16x8*)&wsm[cur][swz(wn * 64 + nf * 16 + ln, kh * 4 + qd)];
      #pragma unroll
      for (int mf = 0; mf < 2; ++mf)
        #pragma unroll
        for (int nf = 0; nf < 4; ++nf)
          acc[mf][nf] = __builtin_amdgcn_mfma_f32_16x16x32_bf16(
              ax[mf], bw[nf], acc[mf][nf], 0, 0, 0);
    }
    __syncthreads();
  }

  const float a = Pa[0];
  #pragma unroll
  for (int nf = 0; nf < 4; ++nf) {
    const float bn = Bv[n0 + wn * 64 + nf * 16 + ln];
    #pragma unroll
    for (int mf = 0; mf < 2; ++mf)
      #pragma unroll
      for (int r = 0; r < 4; ++r) {
        float y = acc[mf][nf][r] + bn;
        y = (y >= 0.f) ? y : a * y;
        Out[(size_t)(m0 + wm * 32 + mf * 16 + qd * 4 + r) * EMB +
            n0 + wn * 64 + nf * 16 + ln] = y;
      }
  }
}

extern "C" void kernel_launch(void* const* d_in, const int* in_sizes, int n_in,
                              void* d_out, int out_size, void* d_ws, size_t ws_size,
                              hipStream_t stream) {
  const float* Q  = (const float*)d_in[0];
  const float* K  = (const float*)d_in[1];
  const float* V  = (const float*)d_in[2];
  const float* W  = (const float*)d_in[3];
  const float* Bb = (const float*)d_in[4];
  const float* Pa = (const float*)d_in[5];
  float* Out = (float*)d_out;

  // workspace (bytes): X 0..8M, Kb 8M..16M, Vt 16M..24M, Wb 24M..26M
  char* ws = (char*)d_ws;
  __hip_bfloat16* Xws = (__hip_bfloat16*)(ws);
  __hip_bfloat16* Kb  = (__hip_bfloat16*)(ws + (8u  << 20));
  __hip_bfloat16* Vt  = (__hip_bfloat16*)(ws + (16u << 20));
  __hip_bfloat16* Wb  = (__hip_bfloat16*)(ws + (24u << 20));

  prep      <<<dim3(S_LEN / 64, NH, 3), 256, 0, stream>>>(K, V, W, Kb, Vt, Wb);
  attn_fwd  <<<dim3(S_LEN / 256, NH, 2), 512, 0, stream>>>(Q, Kb, Vt, Xws);
  proj_prelu<<<dim3(2 * S_LEN / 128, EMB / 128), 512, 0, stream>>>(Xws, Wb, Bb, Pa, Out);
}

// Round 9
// 169.217 us; speedup vs baseline: 1.1483x; 1.1483x over previous
//
#include <hip/hip_runtime.h>
#include <hip/hip_bf16.h>

typedef __attribute__((ext_vector_type(8))) short bf16x8;
typedef __attribute__((ext_vector_type(4))) float f32x4;

#define S_LEN 2048
#define EMB   1024
#define NH    16
#define HD    64

// XOR-swizzled LDS addressing: 64-col bf16 tiles, 8-elem (16 B) chunks.
// elem(row, chunk) = row*64 + ((chunk ^ (row&7))*8).
// Verified rounds 6-8: SQ_LDS_BANK_CONFLICT == 0.
__device__ inline int swz(int row, int chunk) {
  return row * 64 + ((chunk ^ (row & 7)) << 3);
}

// K-row permutation: storing K row s at position [s5,s2,s4,s3,s1,s0] makes
// the exp(S^T) C-layout registers exactly the mfma_16x16x32 A-fragment for
// natural-order V; PV uses K=32 MFMA with b128 V reads, no fixup.
// Verified rounds 6-8 (absmax 4.88e-4).
__device__ inline int kperm(int s) {
  return (s & 0x23) | ((s & 0x04) << 2) | ((s & 0x18) >> 1);
}

// Convert 8 contiguous f32 -> 8 bf16 (RNE) packed in a uint4, optional scale.
__device__ inline uint4 cvt8(const float* __restrict__ src, float scale) {
  float4 f0 = ((const float4*)src)[0];
  float4 f1 = ((const float4*)src)[1];
  __hip_bfloat16 t[8];
  t[0] = __float2bfloat16(f0.x * scale);
  t[1] = __float2bfloat16(f0.y * scale);
  t[2] = __float2bfloat16(f0.z * scale);
  t[3] = __float2bfloat16(f0.w * scale);
  t[4] = __float2bfloat16(f1.x * scale);
  t[5] = __float2bfloat16(f1.y * scale);
  t[6] = __float2bfloat16(f1.z * scale);
  t[7] = __float2bfloat16(f1.w * scale);
  return *(uint4*)t;
}

// ---------------------------------------------------------------------------
// prep: z<2 -> K/V reformat for batch b=z; z==2 -> W f32->bf16 convert.
//   Kb[((b*NH+h)*S + s)*64 + d]  (head-major, rows = keys)
//   Vt[((b*NH+h)*64 + d)*S + s]  (transposed, rows = dims)
// ---------------------------------------------------------------------------
__global__ __launch_bounds__(256)
void prep(const float* __restrict__ K, const float* __restrict__ V,
          const float* __restrict__ W,
          __hip_bfloat16* __restrict__ Kb, __hip_bfloat16* __restrict__ Vt,
          __hip_bfloat16* __restrict__ Wb) {
  const int tid = threadIdx.x;
  if (blockIdx.z == 2) {   // W convert: 512 virtual blocks x 2048 elems
    const int widx = blockIdx.y * 32 + blockIdx.x;
    const int i = (widx * 256 + tid) * 8;
    *(uint4*)(Wb + i) = cvt8(W + i, 1.0f);
    return;
  }
  __shared__ float vt[64 * 65];
  const int st = blockIdx.x, h = blockIdx.y, b = blockIdx.z;
  const size_t srcbase = ((size_t)(b * S_LEN + st * 64)) * EMB + h * HD;
  const size_t kvb = ((size_t)(b * NH + h) * S_LEN + st * 64) * HD;
  const size_t vtb = ((size_t)(b * NH + h) * HD) * S_LEN + st * 64;

  for (int c = tid; c < 512; c += 256) {
    const int r = c >> 3, c8 = (c & 7) * 8;
    *(uint4*)(Kb + kvb + r * HD + c8) = cvt8(K + srcbase + (size_t)r * EMB + c8, 1.0f);
    const float* vsrc = V + srcbase + (size_t)r * EMB + c8;
    float4 a = ((const float4*)vsrc)[0];
    float4 d4 = ((const float4*)vsrc)[1];
    float tv[8] = {a.x, a.y, a.z, a.w, d4.x, d4.y, d4.z, d4.w};
    #pragma unroll
    for (int j = 0; j < 8; ++j) vt[r * 65 + c8 + j] = tv[j];
  }
  __syncthreads();
  for (int c = tid; c < 512; c += 256) {
    const int d = c >> 3, s8 = (c & 7) * 8;
    __hip_bfloat16 t[8];
    #pragma unroll
    for (int j = 0; j < 8; ++j)
      t[j] = __float2bfloat16(vt[(s8 + j) * 65 + d]);
    *(uint4*)(Vt + vtb + (size_t)d * S_LEN + s8) = *(uint4*)t;
  }
}

// ---------------------------------------------------------------------------
// Flash attention v9 = R8 register body (qn=2, flat scalars, no spill) in
// 256-thread blocks: 4 waves x 32 queries = 128 q/block, grid 512 = 2
// blocks/CU -> TWO independent barrier groups per CU (R8's regression was
// 1 block/CU: all 8 waves stalled at the same barrier with nothing to
// overlap). Each K/V LDS fragment still feeds 2 MFMAs (qn reuse).
// S^T = K Q^T; exp(S^T) is directly the PV A-operand (kperm'd K rows,
// K=32 PV MFMAs). XOR swizzle: 0 bank conflicts. 1 barrier/iter.
// ---------------------------------------------------------------------------
__global__ __launch_bounds__(256, 2)
void attn_fwd(const float* __restrict__ Q,
              const __hip_bfloat16* __restrict__ Kb,
              const __hip_bfloat16* __restrict__ Vt,
              __hip_bfloat16* __restrict__ O)
{
  __shared__ __align__(16) __hip_bfloat16 qs[128 * 64];     // 16 KB
  __shared__ __align__(16) __hip_bfloat16 ks[2][64 * 64];   // 16 KB [key][dim]
  __shared__ __align__(16) __hip_bfloat16 vs[2][64 * 64];   // 16 KB [dim][key]

  const int qt   = blockIdx.x;
  const int h    = blockIdx.y;
  const int b    = blockIdx.z;
  const int tid  = threadIdx.x;
  const int wave = tid >> 6;
  const int lane = tid & 63;
  const int ln   = lane & 15;
  const int qd   = lane >> 4;

  const size_t baseQ = ((size_t)(b * S_LEN + qt * 128)) * EMB + h * HD;
  const size_t kvb   = ((size_t)(b * NH + h) * S_LEN) * HD;
  const size_t vtb   = ((size_t)(b * NH + h) * HD) * S_LEN;

  // K/V staging: 512 chunks per tile, 256 threads -> 2 chunks each
  const int ra = tid >> 3, rb = ra + 32, cc = tid & 7;
  const int kpa = swz(kperm(ra), cc), kpb = swz(kperm(rb), cc);
  const int vpa = swz(ra, cc),        vpb = swz(rb, cc);

  // prefetch tile 0 (flat scalars -- no 2-D arrays, avoids scratch demotion)
  uint4 krg0 = *(const uint4*)(Kb + kvb + (size_t)ra * HD + cc * 8);
  uint4 krg1 = *(const uint4*)(Kb + kvb + (size_t)rb * HD + cc * 8);
  uint4 vrg0 = *(const uint4*)(Vt + vtb + (size_t)ra * S_LEN + cc * 8);
  uint4 vrg1 = *(const uint4*)(Vt + vtb + (size_t)rb * S_LEN + cc * 8);

  // stage Q: 128 rows x 8 chunks = 1024 chunks, 4 per thread
  const float qscale = 0.125f * 1.44269504088896f;   // 1/sqrt(64) * log2(e)
  #pragma unroll
  for (int i = 0; i < 4; ++i) {
    const int c = tid + 256 * i, row = c >> 3, ch = c & 7;
    *(uint4*)&qs[swz(row, ch)] = cvt8(Q + baseQ + (size_t)row * EMB + ch * 8, qscale);
  }
  // write tile 0, prefetch tile 1
  *(uint4*)&ks[0][kpa] = krg0;  *(uint4*)&ks[0][kpb] = krg1;
  *(uint4*)&vs[0][vpa] = vrg0;  *(uint4*)&vs[0][vpb] = vrg1;
  krg0 = *(const uint4*)(Kb + kvb + (size_t)(64 + ra) * HD + cc * 8);
  krg1 = *(const uint4*)(Kb + kvb + (size_t)(64 + rb) * HD + cc * 8);
  vrg0 = *(const uint4*)(Vt + vtb + (size_t)ra * S_LEN + 64 + cc * 8);
  vrg1 = *(const uint4*)(Vt + vtb + (size_t)rb * S_LEN + 64 + cc * 8);
  __syncthreads();   // qs + buf0 ready

  // Q B-fragments (n = query = ln, k = qd*8+j), loop-invariant
  bf16x8 aq0[2], aq1[2];
  #pragma unroll
  for (int kh = 0; kh < 2; ++kh) {
    aq0[kh] = *(const bf16x8*)&qs[swz(wave * 32 + ln,      kh * 4 + qd)];
    aq1[kh] = *(const bf16x8*)&qs[swz(wave * 32 + 16 + ln, kh * 4 + qd)];
  }

  f32x4 oacc0[4] = {}, oacc1[4] = {};   // [dn]; C: col=dim=ln, row=qd*4+r
  float lsum0 = 0.f, lsum1 = 0.f;

  for (int kt = 0; kt < S_LEN / 64; ++kt) {
    const int cur = kt & 1;
    if (kt + 1 < S_LEN / 64) {     // regs loaded one full iter ago: no stall
      *(uint4*)&ks[1 - cur][kpa] = krg0;  *(uint4*)&ks[1 - cur][kpb] = krg1;
      *(uint4*)&vs[1 - cur][vpa] = vrg0;  *(uint4*)&vs[1 - cur][vpb] = vrg1;
      if (kt + 2 < S_LEN / 64) {
        const size_t ko = kvb + (size_t)(kt + 2) * 64 * HD;
        krg0 = *(const uint4*)(Kb + ko + (size_t)ra * HD + cc * 8);
        krg1 = *(const uint4*)(Kb + ko + (size_t)rb * HD + cc * 8);
        const size_t vo = vtb + (size_t)(kt + 2) * 64;
        vrg0 = *(const uint4*)(Vt + vo + (size_t)ra * S_LEN + cc * 8);
        vrg1 = *(const uint4*)(Vt + vo + (size_t)rb * S_LEN + cc * 8);
      }
    }

    // ---- S^T = K Q^T (rows = permuted keys); K fragments shared by qn ----
    f32x4 sf0[4], sf1[4];
    #pragma unroll
    for (int kt16 = 0; kt16 < 4; ++kt16) {
      bf16x8 ak0 = *(const bf16x8*)&ks[cur][swz(kt16 * 16 + ln, qd)];
      bf16x8 ak1 = *(const bf16x8*)&ks[cur][swz(kt16 * 16 + ln, 4 + qd)];
      f32x4 a0 = {}, a1 = {};
      a0 = __builtin_amdgcn_mfma_f32_16x16x32_bf16(ak0, aq0[0], a0, 0, 0, 0);
      a0 = __builtin_amdgcn_mfma_f32_16x16x32_bf16(ak1, aq0[1], a0, 0, 0, 0);
      a1 = __builtin_amdgcn_mfma_f32_16x16x32_bf16(ak0, aq1[0], a1, 0, 0, 0);
      a1 = __builtin_amdgcn_mfma_f32_16x16x32_bf16(ak1, aq1[1], a1, 0, 0, 0);
      sf0[kt16] = a0;
      sf1[kt16] = a1;
    }

    // ---- P = exp2(S'); pack straight into K=32 A-fragments ----
    // key at k-index qd*8+j lives at S^T tile kt16 = t*2+(j>>2), reg j&3
    bf16x8 ap0[2], ap1[2];
    #pragma unroll
    for (int t = 0; t < 2; ++t)
      #pragma unroll
      for (int j = 0; j < 8; ++j) {
        const float p0 = exp2f(sf0[t * 2 + (j >> 2)][j & 3]);
        const float p1 = exp2f(sf1[t * 2 + (j >> 2)][j & 3]);
        lsum0 += p0;
        lsum1 += p1;
        __hip_bfloat16 h0 = __float2bfloat16(p0);
        __hip_bfloat16 h1 = __float2bfloat16(p1);
        ap0[t][j] = *(short*)&h0;
        ap1[t][j] = *(short*)&h1;
      }

    // ---- O += P V : K=32 MFMA, b128 V reads shared by qn ----
    #pragma unroll
    for (int t = 0; t < 2; ++t)
      #pragma unroll
      for (int dn = 0; dn < 4; ++dn) {
        bf16x8 bv = *(const bf16x8*)&vs[cur][swz(dn * 16 + ln, t * 4 + qd)];
        oacc0[dn] = __builtin_amdgcn_mfma_f32_16x16x32_bf16(ap0[t], bv, oacc0[dn], 0, 0, 0);
        oacc1[dn] = __builtin_amdgcn_mfma_f32_16x16x32_bf16(ap1[t], bv, oacc1[dn], 0, 0, 0);
      }

    __syncthreads();   // single barrier per iteration
  }

  // ---- epilogue: reduce lsum across quads, redistribute, normalize ----
  lsum0 += __shfl_xor(lsum0, 16);
  lsum0 += __shfl_xor(lsum0, 32);
  lsum1 += __shfl_xor(lsum1, 16);
  lsum1 += __shfl_xor(lsum1, 32);
  #pragma unroll
  for (int r = 0; r < 4; ++r) {
    const float inv0 = 1.f / __shfl(lsum0, qd * 4 + r);
    const float inv1 = 1.f / __shfl(lsum1, qd * 4 + r);
    const int row0 = wave * 32 + qd * 4 + r;
    const int row1 = row0 + 16;
    #pragma unroll
    for (int dn = 0; dn < 4; ++dn) {
      O[baseQ + (size_t)row0 * EMB + dn * 16 + ln] =
          __float2bfloat16(oacc0[dn][r] * inv0);
      O[baseQ + (size_t)row1 * EMB + dn * 16 + ln] =
          __float2bfloat16(oacc1[dn][r] * inv1);
    }
  }
}

// ---------------------------------------------------------------------------
// Projection v3: Out = PReLU(X @ W^T + b). 128(M) x 64(N) tile, 512 thr =
// 8 waves x 16 rows (nf=4 col-frags each). Grid 32x16 = 512 blocks = 2/CU
// (two barrier groups -- the 1-block/CU R5-R8 grid was latency-bound).
// XOR-swizzled LDS (conflict-free), double-buffered, 1 barrier/iter.
// ---------------------------------------------------------------------------
__global__ __launch_bounds__(512, 2)
void proj_prelu(const __hip_bfloat16* __restrict__ X,
                const __hip_bfloat16* __restrict__ Wb,
                const float* __restrict__ Bv,
                const float* __restrict__ Pa,
                float* __restrict__ Out)
{
  __shared__ __align__(16) __hip_bfloat16 xs[2][128 * 64];   // 32 KB
  __shared__ __align__(16) __hip_bfloat16 wsm[2][64 * 64];   // 16 KB

  const int m0   = blockIdx.x * 128;
  const int n0   = blockIdx.y * 64;
  const int tid  = threadIdx.x;
  const int wave = tid >> 6;       // 16-row strip
  const int lane = tid & 63;
  const int ln   = lane & 15;
  const int qd   = lane >> 4;

  // staging: xs 1024 chunks -> 2/thread; wsm 512 chunks -> 1/thread
  const int ra = tid >> 3, rb = ra + 64, cc = tid & 7;
  const int pxa = swz(ra, cc), pxb = swz(rb, cc);
  const int rw  = tid >> 3;        // 0..63
  const int pw  = swz(rw, cc);

  f32x4 acc[4] = {};   // [nf]

  uint4 xg0 = *(const uint4*)(X  + (size_t)(m0 + ra) * EMB + cc * 8);
  uint4 xg1 = *(const uint4*)(X  + (size_t)(m0 + rb) * EMB + cc * 8);
  uint4 wg0 = *(const uint4*)(Wb + (size_t)(n0 + rw) * EMB + cc * 8);
  *(uint4*)&xs[0][pxa] = xg0;
  *(uint4*)&xs[0][pxb] = xg1;
  *(uint4*)&wsm[0][pw] = wg0;
  xg0 = *(const uint4*)(X  + (size_t)(m0 + ra) * EMB + 64 + cc * 8);
  xg1 = *(const uint4*)(X  + (size_t)(m0 + rb) * EMB + 64 + cc * 8);
  wg0 = *(const uint4*)(Wb + (size_t)(n0 + rw) * EMB + 64 + cc * 8);
  __syncthreads();

  for (int kt = 0; kt < EMB / 64; ++kt) {
    const int cur = kt & 1;
    if (kt + 1 < EMB / 64) {
      *(uint4*)&xs[1 - cur][pxa] = xg0;
      *(uint4*)&xs[1 - cur][pxb] = xg1;
      *(uint4*)&wsm[1 - cur][pw] = wg0;
      if (kt + 2 < EMB / 64) {
        const int ko = (kt + 2) * 64;
        xg0 = *(const uint4*)(X  + (size_t)(m0 + ra) * EMB + ko + cc * 8);
        xg1 = *(const uint4*)(X  + (size_t)(m0 + rb) * EMB + ko + cc * 8);
        wg0 = *(const uint4*)(Wb + (size_t)(n0 + rw) * EMB + ko + cc * 8);
      }
    }

    #pragma unroll
    for (int kh = 0; kh < 2; ++kh) {
      bf16x8 ax = *(const bf16x8*)&xs[cur][swz(wave * 16 + ln, kh * 4 + qd)];
      #pragma unroll
      for (int nf = 0; nf < 4; ++nf) {
        bf16x8 bw = *(const bf16x8*)&wsm[cur][swz(nf * 16 + ln, kh * 4 + qd)];
        acc[nf] = __builtin_amdgcn_mfma_f32_16x16x32_bf16(ax, bw, acc[nf], 0, 0, 0);
      }
    }
    __syncthreads();
  }

  const float a = Pa[0];
  #pragma unroll
  for (int nf = 0; nf < 4; ++nf) {
    const float bn = Bv[n0 + nf * 16 + ln];
    #pragma unroll
    for (int r = 0; r < 4; ++r) {
      float y = acc[nf][r] + bn;
      y = (y >= 0.f) ? y : a * y;
      Out[(size_t)(m0 + wave * 16 + qd * 4 + r) * EMB + n0 + nf * 16 + ln] = y;
    }
  }
}

extern "C" void kernel_launch(void* const* d_in, const int* in_sizes, int n_in,
                              void* d_out, int out_size, void* d_ws, size_t ws_size,
                              hipStream_t stream) {
  const float* Q  = (const float*)d_in[0];
  const float* K  = (const float*)d_in[1];
  const float* V  = (const float*)d_in[2];
  const float* W  = (const float*)d_in[3];
  const float* Bb = (const float*)d_in[4];
  const float* Pa = (const float*)d_in[5];
  float* Out = (float*)d_out;

  // workspace (bytes): X 0..8M, Kb 8M..16M, Vt 16M..24M, Wb 24M..26M
  char* ws = (char*)d_ws;
  __hip_bfloat16* Xws = (__hip_bfloat16*)(ws);
  __hip_bfloat16* Kb  = (__hip_bfloat16*)(ws + (8u  << 20));
  __hip_bfloat16* Vt  = (__hip_bfloat16*)(ws + (16u << 20));
  __hip_bfloat16* Wb  = (__hip_bfloat16*)(ws + (24u << 20));

  prep      <<<dim3(S_LEN / 64, NH, 3), 256, 0, stream>>>(K, V, W, Kb, Vt, Wb);
  attn_fwd  <<<dim3(S_LEN / 128, NH, 2), 256, 0, stream>>>(Q, Kb, Vt, Xws);
  proj_prelu<<<dim3(2 * S_LEN / 128, EMB / 64), 512, 0, stream>>>(Xws, Wb, Bb, Pa, Out);
}

// Round 10
// 164.462 us; speedup vs baseline: 1.1816x; 1.0289x over previous
//
#include <hip/hip_runtime.h>
#include <hip/hip_bf16.h>

typedef __attribute__((ext_vector_type(8))) short bf16x8;
typedef __attribute__((ext_vector_type(4))) float f32x4;

#define S_LEN 2048
#define EMB   1024
#define NH    16
#define HD    64

// XOR-swizzled LDS addressing: 64-col bf16 tiles, 8-elem (16 B) chunks.
// elem(row, chunk) = row*64 + ((chunk ^ (row&7))*8).
// Verified rounds 6-9: SQ_LDS_BANK_CONFLICT == 0.
__device__ inline int swz(int row, int chunk) {
  return row * 64 + ((chunk ^ (row & 7)) << 3);
}

// K-row permutation: storing K row s at position [s5,s2,s4,s3,s1,s0] makes
// the exp(S^T) C-layout registers exactly the mfma_16x16x32 A-fragment for
// natural-order V; PV uses K=32 MFMA with b128 V reads, no fixup.
// Verified rounds 6-9 (absmax 4.88e-4).
__device__ inline int kperm(int s) {
  return (s & 0x23) | ((s & 0x04) << 2) | ((s & 0x18) >> 1);
}

// Convert 8 contiguous f32 -> 8 bf16 (RNE) packed in a uint4, optional scale.
__device__ inline uint4 cvt8(const float* __restrict__ src, float scale) {
  float4 f0 = ((const float4*)src)[0];
  float4 f1 = ((const float4*)src)[1];
  __hip_bfloat16 t[8];
  t[0] = __float2bfloat16(f0.x * scale);
  t[1] = __float2bfloat16(f0.y * scale);
  t[2] = __float2bfloat16(f0.z * scale);
  t[3] = __float2bfloat16(f0.w * scale);
  t[4] = __float2bfloat16(f1.x * scale);
  t[5] = __float2bfloat16(f1.y * scale);
  t[6] = __float2bfloat16(f1.z * scale);
  t[7] = __float2bfloat16(f1.w * scale);
  return *(uint4*)t;
}

// ---------------------------------------------------------------------------
// prep: z<2 -> K/V reformat for batch b=z; z==2 -> W f32->bf16 convert.
//   Kb[((b*NH+h)*S + s)*64 + d]  (head-major, rows = keys)
//   Vt[((b*NH+h)*64 + d)*S + s]  (transposed, rows = dims)
// ---------------------------------------------------------------------------
__global__ __launch_bounds__(256)
void prep(const float* __restrict__ K, const float* __restrict__ V,
          const float* __restrict__ W,
          __hip_bfloat16* __restrict__ Kb, __hip_bfloat16* __restrict__ Vt,
          __hip_bfloat16* __restrict__ Wb) {
  const int tid = threadIdx.x;
  if (blockIdx.z == 2) {   // W convert: 512 virtual blocks x 2048 elems
    const int widx = blockIdx.y * 32 + blockIdx.x;
    const int i = (widx * 256 + tid) * 8;
    *(uint4*)(Wb + i) = cvt8(W + i, 1.0f);
    return;
  }
  __shared__ float vt[64 * 65];
  const int st = blockIdx.x, h = blockIdx.y, b = blockIdx.z;
  const size_t srcbase = ((size_t)(b * S_LEN + st * 64)) * EMB + h * HD;
  const size_t kvb = ((size_t)(b * NH + h) * S_LEN + st * 64) * HD;
  const size_t vtb = ((size_t)(b * NH + h) * HD) * S_LEN + st * 64;

  for (int c = tid; c < 512; c += 256) {
    const int r = c >> 3, c8 = (c & 7) * 8;
    *(uint4*)(Kb + kvb + r * HD + c8) = cvt8(K + srcbase + (size_t)r * EMB + c8, 1.0f);
    const float* vsrc = V + srcbase + (size_t)r * EMB + c8;
    float4 a = ((const float4*)vsrc)[0];
    float4 d4 = ((const float4*)vsrc)[1];
    float tv[8] = {a.x, a.y, a.z, a.w, d4.x, d4.y, d4.z, d4.w};
    #pragma unroll
    for (int j = 0; j < 8; ++j) vt[r * 65 + c8 + j] = tv[j];
  }
  __syncthreads();
  for (int c = tid; c < 512; c += 256) {
    const int d = c >> 3, s8 = (c & 7) * 8;
    __hip_bfloat16 t[8];
    #pragma unroll
    for (int j = 0; j < 8; ++j)
      t[j] = __float2bfloat16(vt[(s8 + j) * 65 + d]);
    *(uint4*)(Vt + vtb + (size_t)d * S_LEN + s8) = *(uint4*)t;
  }
}

// ---------------------------------------------------------------------------
// Flash attention — R7 config verbatim (best measured: 62.5 us, VGPR 44,
// 0 conflicts, no spill). 512 thr = 8 waves x 16 queries, grid 512 = 2
// blocks/CU = 16 waves/CU (empirically the controlling variable: 16 waves
// -> 62.5 us; 8 waves -> 67-71 us regardless of barrier-group split).
// S^T = K Q^T; exp(S^T) is directly the PV A-operand (kperm'd K rows,
// K=32 PV MFMAs, b128 V reads). Double-buffered, 1 barrier/iter.
// ---------------------------------------------------------------------------
__global__ __launch_bounds__(512, 4)
void attn_fwd(const float* __restrict__ Q,
              const __hip_bfloat16* __restrict__ Kb,
              const __hip_bfloat16* __restrict__ Vt,
              __hip_bfloat16* __restrict__ O)
{
  __shared__ __align__(16) __hip_bfloat16 qs[128 * 64];     // 16 KB
  __shared__ __align__(16) __hip_bfloat16 ks[2][64 * 64];   // 16 KB [key][dim]
  __shared__ __align__(16) __hip_bfloat16 vs[2][64 * 64];   // 16 KB [dim][key]

  const int qt   = blockIdx.x;
  const int h    = blockIdx.y;
  const int b    = blockIdx.z;
  const int tid  = threadIdx.x;
  const int wave = tid >> 6;
  const int lane = tid & 63;
  const int ln   = lane & 15;
  const int qd   = lane >> 4;

  const size_t baseQ = ((size_t)(b * S_LEN + qt * 128)) * EMB + h * HD;
  const size_t kvb   = ((size_t)(b * NH + h) * S_LEN) * HD;
  const size_t vtb   = ((size_t)(b * NH + h) * HD) * S_LEN;

  // staging: 512 chunks per tile, 512 threads -> 1 chunk each
  const int r0 = tid >> 3, cc = tid & 7;
  const int kpos = swz(kperm(r0), cc);   // loop-invariant write addrs
  const int vpos = swz(r0, cc);

  // prefetch tile 0
  uint4 kreg = *(const uint4*)(Kb + kvb + (size_t)r0 * HD + cc * 8);
  uint4 vreg = *(const uint4*)(Vt + vtb + (size_t)r0 * S_LEN + cc * 8);

  // stage Q (f32 -> bf16, scale = 0.125*log2(e); P = exp2(S'))
  const float qscale = 0.125f * 1.44269504088896f;
  #pragma unroll
  for (int i = 0; i < 2; ++i) {
    const int c = tid + 512 * i, row = c >> 3, ch = c & 7;
    *(uint4*)&qs[swz(row, ch)] = cvt8(Q + baseQ + (size_t)row * EMB + ch * 8, qscale);
  }
  // write tile 0, prefetch tile 1
  *(uint4*)&ks[0][kpos] = kreg;
  *(uint4*)&vs[0][vpos] = vreg;
  kreg = *(const uint4*)(Kb + kvb + (size_t)(64 + r0) * HD + cc * 8);
  vreg = *(const uint4*)(Vt + vtb + (size_t)r0 * S_LEN + 64 + cc * 8);
  __syncthreads();   // qs + buf0 ready

  // Q B-fragments (n = query = ln, k = qd*8+j), loop-invariant
  bf16x8 aq[2];
  #pragma unroll
  for (int kh = 0; kh < 2; ++kh)
    aq[kh] = *(const bf16x8*)&qs[swz(wave * 16 + ln, kh * 4 + qd)];

  f32x4 oacc[4] = {};   // [dn]; C: col=dim=ln, row=query=qd*4+r
  float lsum = 0.f;

  for (int kt = 0; kt < S_LEN / 64; ++kt) {
    const int cur = kt & 1;
    if (kt + 1 < S_LEN / 64) {     // regs loaded one full iter ago: no stall
      *(uint4*)&ks[1 - cur][kpos] = kreg;
      *(uint4*)&vs[1 - cur][vpos] = vreg;
      if (kt + 2 < S_LEN / 64) {
        kreg = *(const uint4*)(Kb + kvb + (size_t)((kt + 2) * 64 + r0) * HD + cc * 8);
        vreg = *(const uint4*)(Vt + vtb + (size_t)r0 * S_LEN + (kt + 2) * 64 + cc * 8);
      }
    }

    // ---- S^T = K Q^T (rows = permuted keys) ----
    f32x4 sf[4];
    #pragma unroll
    for (int kt16 = 0; kt16 < 4; ++kt16) {
      bf16x8 ak0 = *(const bf16x8*)&ks[cur][swz(kt16 * 16 + ln, qd)];
      bf16x8 ak1 = *(const bf16x8*)&ks[cur][swz(kt16 * 16 + ln, 4 + qd)];
      f32x4 acc = {};
      acc = __builtin_amdgcn_mfma_f32_16x16x32_bf16(ak0, aq[0], acc, 0, 0, 0);
      acc = __builtin_amdgcn_mfma_f32_16x16x32_bf16(ak1, aq[1], acc, 0, 0, 0);
      sf[kt16] = acc;
    }

    // ---- P = exp2(S'); pack straight into K=32 A-fragments ----
    // key at k-index qd*8+j lives at S^T tile kt16 = t*2+(j>>2), reg j&3
    bf16x8 ap[2];
    #pragma unroll
    for (int t = 0; t < 2; ++t)
      #pragma unroll
      for (int j = 0; j < 8; ++j) {
        const float p = exp2f(sf[t * 2 + (j >> 2)][j & 3]);
        lsum += p;
        __hip_bfloat16 hb = __float2bfloat16(p);
        ap[t][j] = *(short*)&hb;
      }

    // ---- O += P V : K=32 MFMA, b128 V reads from vs[dim][key] ----
    #pragma unroll
    for (int t = 0; t < 2; ++t)
      #pragma unroll
      for (int dn = 0; dn < 4; ++dn) {
        bf16x8 bv = *(const bf16x8*)&vs[cur][swz(dn * 16 + ln, t * 4 + qd)];
        oacc[dn] = __builtin_amdgcn_mfma_f32_16x16x32_bf16(ap[t], bv, oacc[dn], 0, 0, 0);
      }

    __syncthreads();   // single barrier per iteration
  }

  // ---- epilogue: reduce lsum across quads, redistribute, normalize ----
  lsum += __shfl_xor(lsum, 16);
  lsum += __shfl_xor(lsum, 32);
  #pragma unroll
  for (int r = 0; r < 4; ++r) {
    const float inv = 1.f / __shfl(lsum, qd * 4 + r);
    const int row = wave * 16 + qd * 4 + r;
    #pragma unroll
    for (int dn = 0; dn < 4; ++dn)
      O[baseQ + (size_t)row * EMB + dn * 16 + ln] =
          __float2bfloat16(oacc[dn][r] * inv);
  }
}

// ---------------------------------------------------------------------------
// Projection v4 (m97-shaped): Out = PReLU(X @ W^T + b). 128x128 block tile,
// 256 thr = 4 waves in 2x2; each wave computes 64x64 = 4x4 fragments ->
// 32 MFMA per 16 LDS reads per BK=64 iter (2:1, vs 0.8:1 in v3 -- v3 was
// the ~50-65 us hidden cost in the total). Double-buffered staging with
// register prefetch, 1 barrier/iter, XOR swizzle. Grid 32x8 = 256 blocks.
// ---------------------------------------------------------------------------
__global__ __launch_bounds__(256, 2)
void proj_prelu(const __hip_bfloat16* __restrict__ X,
                const __hip_bfloat16* __restrict__ Wb,
                const float* __restrict__ Bv,
                const float* __restrict__ Pa,
                float* __restrict__ Out)
{
  __shared__ __align__(16) __hip_bfloat16 xs[2][128 * 64];   // 32 KB
  __shared__ __align__(16) __hip_bfloat16 wsm[2][128 * 64];  // 32 KB

  const int m0   = blockIdx.x * 128;
  const int n0   = blockIdx.y * 128;
  const int tid  = threadIdx.x;
  const int wave = tid >> 6;
  const int wm   = wave >> 1;      // 0..1 : 64-row half
  const int wn   = wave & 1;       // 0..1 : 64-col half
  const int lane = tid & 63;
  const int ln   = lane & 15;
  const int qd   = lane >> 4;

  // staging: 1024 chunks per array / 256 thr = 4 each (rows r0+32*i)
  const int r0 = tid >> 3, cc = tid & 7;

  f32x4 acc[16] = {};   // [mf*4+nf], flat (R6 lesson: no spillable 2-D)

  uint4 xg0, xg1, xg2, xg3, wg0, wg1, wg2, wg3;
  #define LOADK(ko)                                                        \
    xg0 = *(const uint4*)(X  + (size_t)(m0 + r0     ) * EMB + (ko) + cc * 8); \
    xg1 = *(const uint4*)(X  + (size_t)(m0 + r0 + 32) * EMB + (ko) + cc * 8); \
    xg2 = *(const uint4*)(X  + (size_t)(m0 + r0 + 64) * EMB + (ko) + cc * 8); \
    xg3 = *(const uint4*)(X  + (size_t)(m0 + r0 + 96) * EMB + (ko) + cc * 8); \
    wg0 = *(const uint4*)(Wb + (size_t)(n0 + r0     ) * EMB + (ko) + cc * 8); \
    wg1 = *(const uint4*)(Wb + (size_t)(n0 + r0 + 32) * EMB + (ko) + cc * 8); \
    wg2 = *(const uint4*)(Wb + (size_t)(n0 + r0 + 64) * EMB + (ko) + cc * 8); \
    wg3 = *(const uint4*)(Wb + (size_t)(n0 + r0 + 96) * EMB + (ko) + cc * 8)
  #define STORELDS(buf)                                                    \
    *(uint4*)&xs [buf][swz(r0,      cc)] = xg0;                            \
    *(uint4*)&xs [buf][swz(r0 + 32, cc)] = xg1;                            \
    *(uint4*)&xs [buf][swz(r0 + 64, cc)] = xg2;                            \
    *(uint4*)&xs [buf][swz(r0 + 96, cc)] = xg3;                            \
    *(uint4*)&wsm[buf][swz(r0,      cc)] = wg0;                            \
    *(uint4*)&wsm[buf][swz(r0 + 32, cc)] = wg1;                            \
    *(uint4*)&wsm[buf][swz(r0 + 64, cc)] = wg2;                            \
    *(uint4*)&wsm[buf][swz(r0 + 96, cc)] = wg3

  LOADK(0);
  STORELDS(0);
  LOADK(64);
  __syncthreads();

  for (int kt = 0; kt < EMB / 64; ++kt) {
    const int cur = kt & 1;
    if (kt + 1 < EMB / 64) {
      STORELDS(1 - cur);
      if (kt + 2 < EMB / 64) {
        LOADK((kt + 2) * 64);
      }
    }

    #pragma unroll
    for (int ks2 = 0; ks2 < 2; ++ks2) {   // two K=32 steps
      bf16x8 ax0 = *(const bf16x8*)&xs[cur][swz(wm * 64 +  0 + ln, ks2 * 4 + qd)];
      bf16x8 ax1 = *(const bf16x8*)&xs[cur][swz(wm * 64 + 16 + ln, ks2 * 4 + qd)];
      bf16x8 ax2 = *(const bf16x8*)&xs[cur][swz(wm * 64 + 32 + ln, ks2 * 4 + qd)];
      bf16x8 ax3 = *(const bf16x8*)&xs[cur][swz(wm * 64 + 48 + ln, ks2 * 4 + qd)];
      bf16x8 bw0 = *(const bf16x8*)&wsm[cur][swz(wn * 64 +  0 + ln, ks2 * 4 + qd)];
      bf16x8 bw1 = *(const bf16x8*)&wsm[cur][swz(wn * 64 + 16 + ln, ks2 * 4 + qd)];
      bf16x8 bw2 = *(const bf16x8*)&wsm[cur][swz(wn * 64 + 32 + ln, ks2 * 4 + qd)];
      bf16x8 bw3 = *(const bf16x8*)&wsm[cur][swz(wn * 64 + 48 + ln, ks2 * 4 + qd)];
      acc[ 0] = __builtin_amdgcn_mfma_f32_16x16x32_bf16(ax0, bw0, acc[ 0], 0, 0, 0);
      acc[ 1] = __builtin_amdgcn_mfma_f32_16x16x32_bf16(ax0, bw1, acc[ 1], 0, 0, 0);
      acc[ 2] = __builtin_amdgcn_mfma_f32_16x16x32_bf16(ax0, bw2, acc[ 2], 0, 0, 0);
      acc[ 3] = __builtin_amdgcn_mfma_f32_16x16x32_bf16(ax0, bw3, acc[ 3], 0, 0, 0);
      acc[ 4] = __builtin_amdgcn_mfma_f32_16x16x32_bf16(ax1, bw0, acc[ 4], 0, 0, 0);
      acc[ 5] = __builtin_amdgcn_mfma_f32_16x16x32_bf16(ax1, bw1, acc[ 5], 0, 0, 0);
      acc[ 6] = __builtin_amdgcn_mfma_f32_16x16x32_bf16(ax1, bw2, acc[ 6], 0, 0, 0);
      acc[ 7] = __builtin_amdgcn_mfma_f32_16x16x32_bf16(ax1, bw3, acc[ 7], 0, 0, 0);
      acc[ 8] = __builtin_amdgcn_mfma_f32_16x16x32_bf16(ax2, bw0, acc[ 8], 0, 0, 0);
      acc[ 9] = __builtin_amdgcn_mfma_f32_16x16x32_bf16(ax2, bw1, acc[ 9], 0, 0, 0);
      acc[10] = __builtin_amdgcn_mfma_f32_16x16x32_bf16(ax2, bw2, acc[10], 0, 0, 0);
      acc[11] = __builtin_amdgcn_mfma_f32_16x16x32_bf16(ax2, bw3, acc[11], 0, 0, 0);
      acc[12] = __builtin_amdgcn_mfma_f32_16x16x32_bf16(ax3, bw0, acc[12], 0, 0, 0);
      acc[13] = __builtin_amdgcn_mfma_f32_16x16x32_bf16(ax3, bw1, acc[13], 0, 0, 0);
      acc[14] = __builtin_amdgcn_mfma_f32_16x16x32_bf16(ax3, bw2, acc[14], 0, 0, 0);
      acc[15] = __builtin_amdgcn_mfma_f32_16x16x32_bf16(ax3, bw3, acc[15], 0, 0, 0);
    }
    __syncthreads();
  }

  const float a = Pa[0];
  #pragma unroll
  for (int mf = 0; mf < 4; ++mf) {
    #pragma unroll
    for (int nf = 0; nf < 4; ++nf) {
      const float bn = Bv[n0 + wn * 64 + nf * 16 + ln];
      #pragma unroll
      for (int r = 0; r < 4; ++r) {
        float y = acc[mf * 4 + nf][r] + bn;
        y = (y >= 0.f) ? y : a * y;
        Out[(size_t)(m0 + wm * 64 + mf * 16 + qd * 4 + r) * EMB +
            n0 + wn * 64 + nf * 16 + ln] = y;
      }
    }
  }
  #undef LOADK
  #undef STORELDS
}

extern "C" void kernel_launch(void* const* d_in, const int* in_sizes, int n_in,
                              void* d_out, int out_size, void* d_ws, size_t ws_size,
                              hipStream_t stream) {
  const float* Q  = (const float*)d_in[0];
  const float* K  = (const float*)d_in[1];
  const float* V  = (const float*)d_in[2];
  const float* W  = (const float*)d_in[3];
  const float* Bb = (const float*)d_in[4];
  const float* Pa = (const float*)d_in[5];
  float* Out = (float*)d_out;

  // workspace (bytes): X 0..8M, Kb 8M..16M, Vt 16M..24M, Wb 24M..26M
  char* ws = (char*)d_ws;
  __hip_bfloat16* Xws = (__hip_bfloat16*)(ws);
  __hip_bfloat16* Kb  = (__hip_bfloat16*)(ws + (8u  << 20));
  __hip_bfloat16* Vt  = (__hip_bfloat16*)(ws + (16u << 20));
  __hip_bfloat16* Wb  = (__hip_bfloat16*)(ws + (24u << 20));

  prep      <<<dim3(S_LEN / 64, NH, 3), 256, 0, stream>>>(K, V, W, Kb, Vt, Wb);
  attn_fwd  <<<dim3(S_LEN / 128, NH, 2), 512, 0, stream>>>(Q, Kb, Vt, Xws);
  proj_prelu<<<dim3(2 * S_LEN / 128, EMB / 128), 256, 0, stream>>>(Xws, Wb, Bb, Pa, Out);
}